// Round 22
// baseline (131.040 us; speedup 1.0000x reference)
//
#include <hip/hip_runtime.h>
#include <float.h>

// ReconGraph: out[x][y] = OR over 4 diagonal neighbors of (|d[y+dy][x+dx]-d[y][x]| <= thr),
// OOB neighbor = FLT_MAX (never connects). Output int32 0/1, transposed (out[x*8192+y]).
//
// Round-22: ABLATION — r21 exact but pass2 uses PLAIN stores (not nontemporal).
// fillBuffer reaches 6.9 TB/s with regular stores (L2 write-combining); nt bypasses L2.
// Single variable vs r21 (100.6 us): attributes nt's contribution.
//  pass 1: r21 exact (transposed bm, two uint4 nt stores per wave).
//  pass 2: r21 exact addressing (coalesced uint4 bm load, LDS shuffle, 4 KB runs),
//          plain int4 stores.
// Fallback (ws too small): round-6 register-stencil kernel (known-good, 154 us).

typedef int  iv4 __attribute__((ext_vector_type(4)));
typedef unsigned uv4 __attribute__((ext_vector_type(4)));

// ---------------- pass 1 (r21 exact) ----------------
__device__ __forceinline__ void load_row(const float* __restrict__ d, int y, int x0, int xl,
                                         float* r, float& eL, float& eR) {
    if ((unsigned)y < 8192u) {
        const float4 a = *reinterpret_cast<const float4*>(d + ((size_t)y << 13) + xl);
        const float4 b = *reinterpret_cast<const float4*>(d + ((size_t)y << 13) + xl + 4);
        r[0] = a.x; r[1] = a.y; r[2] = a.z; r[3] = a.w;
        r[4] = b.x; r[5] = b.y; r[6] = b.z; r[7] = b.w;
        eL = (x0 > 0)          ? d[((size_t)y << 13) + x0 - 1]   : FLT_MAX;
        eR = (x0 + 512 < 8192) ? d[((size_t)y << 13) + x0 + 512] : FLT_MAX;
    } else {
#pragma unroll
        for (int i = 0; i < 8; ++i) r[i] = FLT_MAX;
        eL = eR = FLT_MAX;
    }
}

__global__ __launch_bounds__(256, 4)
void pass1_kernel(const float* __restrict__ d, const float* __restrict__ thrp,
                  unsigned char* __restrict__ bm) {
    const float thr = thrp[0];
    const int tid  = threadIdx.x;
    const int lane = tid & 63;
    const int wid  = blockIdx.x * 4 + (tid >> 6);   // 0..4095
    const int strip = wid & 15;                     // 16 strips of 512 px
    const int band  = wid >> 4;                     // 256 bands of 32 rows
    const int x0 = strip * 512;
    const int yb = band * 32;
    const int xl = x0 + 8 * lane;                   // lane's 8-px base

    float rA[8], rB[8], rC[8], rD[8];               // rows y-1, y, y+1, prefetch y+2
    float eA, eB, eC, eD, fA, fB, fC, fD;

    load_row(d, yb - 1, x0, xl, rA, eA, fA);
    load_row(d, yb,     x0, xl, rB, eB, fB);
    load_row(d, yb + 1, x0, xl, rC, eC, fC);

    unsigned w[8] = {0, 0, 0, 0, 0, 0, 0, 0};       // 32 y-bytes of lane's xbyte column

    for (int y = yb; y < yb + 32; ++y) {
        const int yn = y + 2;                       // wave-uniform prefetch guard
        if (yn <= yb + 32) load_row(d, yn, x0, xl, rD, eD, fD);

        float lA = __shfl_up(rA[7], 1);   if (lane == 0)  lA = eA;
        float hA = __shfl_down(rA[0], 1); if (lane == 63) hA = fA;
        float lC = __shfl_up(rC[7], 1);   if (lane == 0)  lC = eC;
        float hC = __shfl_down(rC[0], 1); if (lane == 63) hC = fC;

        unsigned byte = 0;
#pragma unroll
        for (int k = 0; k < 8; ++k) {
            const float c  = rB[k];
            const float tl = (k == 0) ? lA : rA[k - 1];
            const float tr = (k == 7) ? hA : rA[k + 1];
            const float bl = (k == 0) ? lC : rC[k - 1];
            const float br = (k == 7) ? hC : rC[k + 1];
            const bool conn = (fabsf(tl - c) <= thr) | (fabsf(tr - c) <= thr) |
                              (fabsf(bl - c) <= thr) | (fabsf(br - c) <= thr);
            byte |= (conn ? 1u : 0u) << k;
        }
        const int i = y - yb;
        w[i >> 2] |= byte << (8 * (i & 3));

#pragma unroll
        for (int q = 0; q < 8; ++q) { rA[q] = rB[q]; rB[q] = rC[q]; rC[q] = rD[q]; }
        eA = eB; eB = eC; eC = eD;
        fA = fB; fB = fC; fC = fD;
    }

    // transposed bm: column (x0/8 + lane), rows yb..yb+31 -> 32 contiguous bytes
    const int col = (x0 >> 3) + lane;
    unsigned char* p = bm + (size_t)col * 8192 + yb;
    uv4 lo; lo.x = w[0]; lo.y = w[1]; lo.z = w[2]; lo.w = w[3];
    uv4 hi; hi.x = w[4]; hi.y = w[5]; hi.z = w[6]; hi.w = w[7];
    __builtin_nontemporal_store(lo, reinterpret_cast<uv4*>(p));
    __builtin_nontemporal_store(hi, reinterpret_cast<uv4*>(p + 16));
}

// ---------------- pass 2 v5: r21 addressing, PLAIN stores ----------------
__global__ __launch_bounds__(256, 8)
void pass2_kernel(const unsigned char* __restrict__ bm, int* __restrict__ out) {
    __shared__ unsigned lds[4][256];                // 1 KB per wave, no cross-wave sharing

    const int tid  = threadIdx.x;
    const int lane = tid & 63;
    const int wv   = tid >> 6;
    const int wid  = blockIdx.x * 4 + wv;           // 0..8191
    const int xcol = wid >> 3;                      // xbyte column 0..1023
    const int yw   = wid & 7;                       // 8 y-windows of 1024
    const int x0 = xcol * 8;
    const int y0 = yw * 1024;

    // coalesced: lane's 16 bytes = y offsets 16*lane .. 16*lane+15
    const uv4 bv = *reinterpret_cast<const uv4*>(bm + (size_t)xcol * 8192 + y0 + 16 * lane);
    lds[wv][4 * lane + 0] = bv.x;
    lds[wv][4 * lane + 1] = bv.y;
    lds[wv][4 * lane + 2] = bv.z;
    lds[wv][4 * lane + 3] = bv.w;
    __builtin_amdgcn_s_waitcnt(0);                  // own-wave LDS writes complete

    unsigned w[4];
#pragma unroll
    for (int c = 0; c < 4; ++c)
        w[c] = lds[wv][c * 64 + lane];              // bytes for y = y0 + c*256 + 4*lane + {0..3}

#pragma unroll
    for (int r = 0; r < 8; ++r) {                   // output row x0+r (bit r of each byte)
        int* rowp = out + ((size_t)(x0 + r) << 13) + y0 + 4 * lane;
#pragma unroll
        for (int c = 0; c < 4; ++c) {               // 4 consecutive 1 KB solid chunks
            iv4 o;
            o.x = (int)((w[c] >> (r))      & 1u);
            o.y = (int)((w[c] >> (r + 8))  & 1u);
            o.z = (int)((w[c] >> (r + 16)) & 1u);
            o.w = (int)((w[c] >> (r + 24)) & 1u);
            *reinterpret_cast<iv4*>(rowp + c * 256) = o;   // PLAIN store (ablation)
        }
    }
}

// ---------------- fallback (round-6, known-good) ----------------
#define BIG4 make_float4(FLT_MAX, FLT_MAX, FLT_MAX, FLT_MAX)

template<bool EDGE>
__device__ __forceinline__ void recon_body(const float* __restrict__ d, float thr,
                                           int* __restrict__ out, int bx, int by, int tid) {
    const int xq = tid & 15;
    const int yq = tid >> 4;
    const int gx = bx * 64 + 4 * xq;
    const int gy = by * 64 + 4 * yq;
    float s[6][6];
#pragma unroll
    for (int j = 0; j < 6; ++j) {
        const int yy = gy - 1 + j;
        float4 a, b, c;
        if (!EDGE) {
            const float4* p = (const float4*)(d + ((size_t)yy << 13) + gx);
            a = p[-1]; b = p[0]; c = p[1];
        } else {
            const bool yok = (unsigned)yy < 8192u;
            const float4* p = (const float4*)(d + ((size_t)(yok ? yy : 0) << 13) + gx);
            a = (yok && gx >= 4)       ? p[-1] : BIG4;
            b = yok                    ? p[0]  : BIG4;
            c = (yok && gx + 7 < 8192) ? p[1]  : BIG4;
        }
        s[j][0] = a.w; s[j][1] = b.x; s[j][2] = b.y;
        s[j][3] = b.z; s[j][4] = b.w; s[j][5] = c.x;
    }
#pragma unroll
    for (int i = 0; i < 4; ++i) {
        int r[4];
#pragma unroll
        for (int k = 0; k < 4; ++k) {
            const float ctr = s[k + 1][i + 1];
            const bool conn = (fabsf(s[k][i]     - ctr) <= thr) |
                              (fabsf(s[k][i + 2] - ctr) <= thr) |
                              (fabsf(s[k + 2][i]     - ctr) <= thr) |
                              (fabsf(s[k + 2][i + 2] - ctr) <= thr);
            r[k] = conn ? 1 : 0;
        }
        *reinterpret_cast<int4*>(out + ((size_t)(gx + i) << 13) + gy) =
            make_int4(r[0], r[1], r[2], r[3]);
    }
}

__global__ __launch_bounds__(256, 4)
void recon_fallback(const float* __restrict__ d, const float* __restrict__ thrp,
                    int* __restrict__ out) {
    const float thr = thrp[0];
    const int bx = blockIdx.x, by = blockIdx.y;
    if (bx >= 1 && bx <= 126 && by >= 1 && by <= 126)
        recon_body<false>(d, thr, out, bx, by, threadIdx.x);
    else
        recon_body<true>(d, thr, out, bx, by, threadIdx.x);
}

extern "C" void kernel_launch(void* const* d_in, const int* in_sizes, int n_in,
                              void* d_out, int out_size, void* d_ws, size_t ws_size,
                              hipStream_t stream) {
    const float* d   = (const float*)d_in[0];
    const float* thr = (const float*)d_in[1];
    int* out = (int*)d_out;
    const size_t BM_BYTES = (size_t)8192 * 1024;   // 8 MB bit-packed mask

    if (ws_size >= BM_BYTES) {
        unsigned char* bm = (unsigned char*)d_ws;
        pass1_kernel<<<1024, 256, 0, stream>>>(d, thr, bm);
        pass2_kernel<<<2048, 256, 0, stream>>>(bm, out);
    } else {
        recon_fallback<<<dim3(128, 128), 256, 0, stream>>>(d, thr, out);
    }
}

// Round 23
// 104.910 us; speedup vs baseline: 1.2491x; 1.2491x over previous
//
#include <hip/hip_runtime.h>
#include <float.h>

// ReconGraph: out[x][y] = OR over 4 diagonal neighbors of (|d[y+dy][x+dx]-d[y][x]| <= thr),
// OOB neighbor = FLT_MAX (never connects). Output int32 0/1, transposed (out[x*8192+y]).
//
// Round-23: clean 8 KB nt-run probe (r19 retried without its gather confound).
//  pass 1: r21 exact (transposed bm, two uint4 nt stores per wave).
//  pass 2 v6: wave = 4 x-rows x 2048 y (8192 waves, occupancy unchanged vs r21);
//             two coalesced uv4 bm loads/lane, LDS shuffle, per x-row 8 consecutive
//             1 KB nt chunks = 8 KB sequential run.
// Fallback (ws too small): round-6 register-stencil kernel (known-good, 154 us).

typedef int  iv4 __attribute__((ext_vector_type(4)));
typedef unsigned uv4 __attribute__((ext_vector_type(4)));

// ---------------- pass 1 (r21 exact) ----------------
__device__ __forceinline__ void load_row(const float* __restrict__ d, int y, int x0, int xl,
                                         float* r, float& eL, float& eR) {
    if ((unsigned)y < 8192u) {
        const float4 a = *reinterpret_cast<const float4*>(d + ((size_t)y << 13) + xl);
        const float4 b = *reinterpret_cast<const float4*>(d + ((size_t)y << 13) + xl + 4);
        r[0] = a.x; r[1] = a.y; r[2] = a.z; r[3] = a.w;
        r[4] = b.x; r[5] = b.y; r[6] = b.z; r[7] = b.w;
        eL = (x0 > 0)          ? d[((size_t)y << 13) + x0 - 1]   : FLT_MAX;
        eR = (x0 + 512 < 8192) ? d[((size_t)y << 13) + x0 + 512] : FLT_MAX;
    } else {
#pragma unroll
        for (int i = 0; i < 8; ++i) r[i] = FLT_MAX;
        eL = eR = FLT_MAX;
    }
}

__global__ __launch_bounds__(256, 4)
void pass1_kernel(const float* __restrict__ d, const float* __restrict__ thrp,
                  unsigned char* __restrict__ bm) {
    const float thr = thrp[0];
    const int tid  = threadIdx.x;
    const int lane = tid & 63;
    const int wid  = blockIdx.x * 4 + (tid >> 6);   // 0..4095
    const int strip = wid & 15;                     // 16 strips of 512 px
    const int band  = wid >> 4;                     // 256 bands of 32 rows
    const int x0 = strip * 512;
    const int yb = band * 32;
    const int xl = x0 + 8 * lane;                   // lane's 8-px base

    float rA[8], rB[8], rC[8], rD[8];               // rows y-1, y, y+1, prefetch y+2
    float eA, eB, eC, eD, fA, fB, fC, fD;

    load_row(d, yb - 1, x0, xl, rA, eA, fA);
    load_row(d, yb,     x0, xl, rB, eB, fB);
    load_row(d, yb + 1, x0, xl, rC, eC, fC);

    unsigned w[8] = {0, 0, 0, 0, 0, 0, 0, 0};       // 32 y-bytes of lane's xbyte column

    for (int y = yb; y < yb + 32; ++y) {
        const int yn = y + 2;                       // wave-uniform prefetch guard
        if (yn <= yb + 32) load_row(d, yn, x0, xl, rD, eD, fD);

        float lA = __shfl_up(rA[7], 1);   if (lane == 0)  lA = eA;
        float hA = __shfl_down(rA[0], 1); if (lane == 63) hA = fA;
        float lC = __shfl_up(rC[7], 1);   if (lane == 0)  lC = eC;
        float hC = __shfl_down(rC[0], 1); if (lane == 63) hC = fC;

        unsigned byte = 0;
#pragma unroll
        for (int k = 0; k < 8; ++k) {
            const float c  = rB[k];
            const float tl = (k == 0) ? lA : rA[k - 1];
            const float tr = (k == 7) ? hA : rA[k + 1];
            const float bl = (k == 0) ? lC : rC[k - 1];
            const float br = (k == 7) ? hC : rC[k + 1];
            const bool conn = (fabsf(tl - c) <= thr) | (fabsf(tr - c) <= thr) |
                              (fabsf(bl - c) <= thr) | (fabsf(br - c) <= thr);
            byte |= (conn ? 1u : 0u) << k;
        }
        const int i = y - yb;
        w[i >> 2] |= byte << (8 * (i & 3));

#pragma unroll
        for (int q = 0; q < 8; ++q) { rA[q] = rB[q]; rB[q] = rC[q]; rC[q] = rD[q]; }
        eA = eB; eB = eC; eC = eD;
        fA = fB; fB = fC; fC = fD;
    }

    // transposed bm: column (x0/8 + lane), rows yb..yb+31 -> 32 contiguous bytes
    const int col = (x0 >> 3) + lane;
    unsigned char* p = bm + (size_t)col * 8192 + yb;
    uv4 lo; lo.x = w[0]; lo.y = w[1]; lo.z = w[2]; lo.w = w[3];
    uv4 hi; hi.x = w[4]; hi.y = w[5]; hi.z = w[6]; hi.w = w[7];
    __builtin_nontemporal_store(lo, reinterpret_cast<uv4*>(p));
    __builtin_nontemporal_store(hi, reinterpret_cast<uv4*>(p + 16));
}

// ---------------- pass 2 v6: 4 x-rows x 2048 y, 8 KB nt runs ----------------
__global__ __launch_bounds__(256, 8)
void pass2_kernel(const unsigned char* __restrict__ bm, int* __restrict__ out) {
    __shared__ unsigned lds[4][512];                // 2 KB per wave

    const int tid  = threadIdx.x;
    const int lane = tid & 63;
    const int wv   = tid >> 6;
    const int wid  = blockIdx.x * 4 + wv;           // 0..8191
    const int xq   = wid >> 2;                      // x-quartet 0..2047
    const int yw   = wid & 3;                       // 4 y-windows of 2048
    const int xcol = xq >> 1;                       // xbyte column 0..1023
    const int b0   = (xq & 1) * 4;                  // bit base of our 4 x-rows
    const int x0 = xq * 4;                          // = xcol*8 + b0
    const int y0 = yw * 2048;

    // two fully-coalesced 1 KB sub-window loads
    const unsigned char* colp = bm + (size_t)xcol * 8192 + y0;
    const uv4 bv0 = *reinterpret_cast<const uv4*>(colp + 16 * lane);
    const uv4 bv1 = *reinterpret_cast<const uv4*>(colp + 1024 + 16 * lane);
    lds[wv][4 * lane + 0] = bv0.x;
    lds[wv][4 * lane + 1] = bv0.y;
    lds[wv][4 * lane + 2] = bv0.z;
    lds[wv][4 * lane + 3] = bv0.w;
    lds[wv][256 + 4 * lane + 0] = bv1.x;
    lds[wv][256 + 4 * lane + 1] = bv1.y;
    lds[wv][256 + 4 * lane + 2] = bv1.z;
    lds[wv][256 + 4 * lane + 3] = bv1.w;
    __builtin_amdgcn_s_waitcnt(0);                  // own-wave LDS writes complete

    unsigned w[8];
#pragma unroll
    for (int c = 0; c < 8; ++c)
        w[c] = lds[wv][c * 64 + lane];              // bytes for y = y0 + c*256 + 4*lane + {0..3}

#pragma unroll
    for (int r = 0; r < 4; ++r) {                   // output row x0+r (bit b0+r of each byte)
        const int bit = b0 + r;
        int* rowp = out + ((size_t)(x0 + r) << 13) + y0 + 4 * lane;
#pragma unroll
        for (int c = 0; c < 8; ++c) {               // 8 consecutive 1 KB chunks = 8 KB run
            iv4 o;
            o.x = (int)((w[c] >> (bit))      & 1u);
            o.y = (int)((w[c] >> (bit + 8))  & 1u);
            o.z = (int)((w[c] >> (bit + 16)) & 1u);
            o.w = (int)((w[c] >> (bit + 24)) & 1u);
            __builtin_nontemporal_store(o, reinterpret_cast<iv4*>(rowp + c * 256));
        }
    }
}

// ---------------- fallback (round-6, known-good) ----------------
#define BIG4 make_float4(FLT_MAX, FLT_MAX, FLT_MAX, FLT_MAX)

template<bool EDGE>
__device__ __forceinline__ void recon_body(const float* __restrict__ d, float thr,
                                           int* __restrict__ out, int bx, int by, int tid) {
    const int xq = tid & 15;
    const int yq = tid >> 4;
    const int gx = bx * 64 + 4 * xq;
    const int gy = by * 64 + 4 * yq;
    float s[6][6];
#pragma unroll
    for (int j = 0; j < 6; ++j) {
        const int yy = gy - 1 + j;
        float4 a, b, c;
        if (!EDGE) {
            const float4* p = (const float4*)(d + ((size_t)yy << 13) + gx);
            a = p[-1]; b = p[0]; c = p[1];
        } else {
            const bool yok = (unsigned)yy < 8192u;
            const float4* p = (const float4*)(d + ((size_t)(yok ? yy : 0) << 13) + gx);
            a = (yok && gx >= 4)       ? p[-1] : BIG4;
            b = yok                    ? p[0]  : BIG4;
            c = (yok && gx + 7 < 8192) ? p[1]  : BIG4;
        }
        s[j][0] = a.w; s[j][1] = b.x; s[j][2] = b.y;
        s[j][3] = b.z; s[j][4] = b.w; s[j][5] = c.x;
    }
#pragma unroll
    for (int i = 0; i < 4; ++i) {
        int r[4];
#pragma unroll
        for (int k = 0; k < 4; ++k) {
            const float ctr = s[k + 1][i + 1];
            const bool conn = (fabsf(s[k][i]     - ctr) <= thr) |
                              (fabsf(s[k][i + 2] - ctr) <= thr) |
                              (fabsf(s[k + 2][i]     - ctr) <= thr) |
                              (fabsf(s[k + 2][i + 2] - ctr) <= thr);
            r[k] = conn ? 1 : 0;
        }
        *reinterpret_cast<int4*>(out + ((size_t)(gx + i) << 13) + gy) =
            make_int4(r[0], r[1], r[2], r[3]);
    }
}

__global__ __launch_bounds__(256, 4)
void recon_fallback(const float* __restrict__ d, const float* __restrict__ thrp,
                    int* __restrict__ out) {
    const float thr = thrp[0];
    const int bx = blockIdx.x, by = blockIdx.y;
    if (bx >= 1 && bx <= 126 && by >= 1 && by <= 126)
        recon_body<false>(d, thr, out, bx, by, threadIdx.x);
    else
        recon_body<true>(d, thr, out, bx, by, threadIdx.x);
}

extern "C" void kernel_launch(void* const* d_in, const int* in_sizes, int n_in,
                              void* d_out, int out_size, void* d_ws, size_t ws_size,
                              hipStream_t stream) {
    const float* d   = (const float*)d_in[0];
    const float* thr = (const float*)d_in[1];
    int* out = (int*)d_out;
    const size_t BM_BYTES = (size_t)8192 * 1024;   // 8 MB bit-packed mask

    if (ws_size >= BM_BYTES) {
        unsigned char* bm = (unsigned char*)d_ws;
        pass1_kernel<<<1024, 256, 0, stream>>>(d, thr, bm);
        pass2_kernel<<<2048, 256, 0, stream>>>(bm, out);
    } else {
        recon_fallback<<<dim3(128, 128), 256, 0, stream>>>(d, thr, out);
    }
}

// Round 24
// 100.639 us; speedup vs baseline: 1.3021x; 1.0424x over previous
//
#include <hip/hip_runtime.h>
#include <float.h>

// ReconGraph: out[x][y] = OR over 4 diagonal neighbors of (|d[y+dy][x+dx]-d[y][x]| <= thr),
// OOB neighbor = FLT_MAX (never connects). Output int32 0/1, transposed (out[x*8192+y]).
//
// FINAL (r21, best measured: 100.6 us = composite roofline).
// Two-pass bit-domain transpose:
//  pass 1 (46.5 us, ~5.8 TB/s read): row-order rolling 3-row register stencil,
//          512-px strips x 32-row bands; lane accumulates its xbyte column as 8 u32,
//          two uint4 nt stores to TRANSPOSED bitmask bm[xbyte][y] (8 MB in d_ws).
//  pass 2 (54 us, ~4.9 TB/s nt-write ceiling): wave = 8 x-rows x 1024 y; one coalesced
//          uint4 bm load per lane, per-wave LDS shuffle (no barrier), per x-row
//          4 consecutive 1 KB nontemporal chunks = 4 KB runs (measured optimum:
//          1 KB +30us, 8 KB +4us, plain stores +30us via L2/L3 churn).
// Fallback (ws too small): round-6 register-stencil kernel (known-good, 154 us).

typedef int  iv4 __attribute__((ext_vector_type(4)));
typedef unsigned uv4 __attribute__((ext_vector_type(4)));

// ---------------- pass 1 ----------------
__device__ __forceinline__ void load_row(const float* __restrict__ d, int y, int x0, int xl,
                                         float* r, float& eL, float& eR) {
    if ((unsigned)y < 8192u) {
        const float4 a = *reinterpret_cast<const float4*>(d + ((size_t)y << 13) + xl);
        const float4 b = *reinterpret_cast<const float4*>(d + ((size_t)y << 13) + xl + 4);
        r[0] = a.x; r[1] = a.y; r[2] = a.z; r[3] = a.w;
        r[4] = b.x; r[5] = b.y; r[6] = b.z; r[7] = b.w;
        eL = (x0 > 0)          ? d[((size_t)y << 13) + x0 - 1]   : FLT_MAX;
        eR = (x0 + 512 < 8192) ? d[((size_t)y << 13) + x0 + 512] : FLT_MAX;
    } else {
#pragma unroll
        for (int i = 0; i < 8; ++i) r[i] = FLT_MAX;
        eL = eR = FLT_MAX;
    }
}

__global__ __launch_bounds__(256, 4)
void pass1_kernel(const float* __restrict__ d, const float* __restrict__ thrp,
                  unsigned char* __restrict__ bm) {
    const float thr = thrp[0];
    const int tid  = threadIdx.x;
    const int lane = tid & 63;
    const int wid  = blockIdx.x * 4 + (tid >> 6);   // 0..4095
    const int strip = wid & 15;                     // 16 strips of 512 px
    const int band  = wid >> 4;                     // 256 bands of 32 rows
    const int x0 = strip * 512;
    const int yb = band * 32;
    const int xl = x0 + 8 * lane;                   // lane's 8-px base

    float rA[8], rB[8], rC[8], rD[8];               // rows y-1, y, y+1, prefetch y+2
    float eA, eB, eC, eD, fA, fB, fC, fD;

    load_row(d, yb - 1, x0, xl, rA, eA, fA);
    load_row(d, yb,     x0, xl, rB, eB, fB);
    load_row(d, yb + 1, x0, xl, rC, eC, fC);

    unsigned w[8] = {0, 0, 0, 0, 0, 0, 0, 0};       // 32 y-bytes of lane's xbyte column

    for (int y = yb; y < yb + 32; ++y) {
        const int yn = y + 2;                       // wave-uniform prefetch guard
        if (yn <= yb + 32) load_row(d, yn, x0, xl, rD, eD, fD);

        float lA = __shfl_up(rA[7], 1);   if (lane == 0)  lA = eA;
        float hA = __shfl_down(rA[0], 1); if (lane == 63) hA = fA;
        float lC = __shfl_up(rC[7], 1);   if (lane == 0)  lC = eC;
        float hC = __shfl_down(rC[0], 1); if (lane == 63) hC = fC;

        unsigned byte = 0;
#pragma unroll
        for (int k = 0; k < 8; ++k) {
            const float c  = rB[k];
            const float tl = (k == 0) ? lA : rA[k - 1];
            const float tr = (k == 7) ? hA : rA[k + 1];
            const float bl = (k == 0) ? lC : rC[k - 1];
            const float br = (k == 7) ? hC : rC[k + 1];
            const bool conn = (fabsf(tl - c) <= thr) | (fabsf(tr - c) <= thr) |
                              (fabsf(bl - c) <= thr) | (fabsf(br - c) <= thr);
            byte |= (conn ? 1u : 0u) << k;
        }
        const int i = y - yb;
        w[i >> 2] |= byte << (8 * (i & 3));

#pragma unroll
        for (int q = 0; q < 8; ++q) { rA[q] = rB[q]; rB[q] = rC[q]; rC[q] = rD[q]; }
        eA = eB; eB = eC; eC = eD;
        fA = fB; fB = fC; fC = fD;
    }

    // transposed bm: column (x0/8 + lane), rows yb..yb+31 -> 32 contiguous bytes
    const int col = (x0 >> 3) + lane;
    unsigned char* p = bm + (size_t)col * 8192 + yb;
    uv4 lo; lo.x = w[0]; lo.y = w[1]; lo.z = w[2]; lo.w = w[3];
    uv4 hi; hi.x = w[4]; hi.y = w[5]; hi.z = w[6]; hi.w = w[7];
    __builtin_nontemporal_store(lo, reinterpret_cast<uv4*>(p));
    __builtin_nontemporal_store(hi, reinterpret_cast<uv4*>(p + 16));
}

// ---------------- pass 2 ----------------
// wave = 8 x-rows (one xbyte column) x 1024 y. One coalesced uint4 bm load per lane,
// LDS shuffle to the y<->lane map, 4 x 1KB-solid nt store runs per x-row.
__global__ __launch_bounds__(256, 8)
void pass2_kernel(const unsigned char* __restrict__ bm, int* __restrict__ out) {
    __shared__ unsigned lds[4][256];                // 1 KB per wave, no cross-wave sharing

    const int tid  = threadIdx.x;
    const int lane = tid & 63;
    const int wv   = tid >> 6;
    const int wid  = blockIdx.x * 4 + wv;           // 0..8191
    const int xcol = wid >> 3;                      // xbyte column 0..1023
    const int yw   = wid & 7;                       // 8 y-windows of 1024
    const int x0 = xcol * 8;
    const int y0 = yw * 1024;

    // coalesced: lane's 16 bytes = y offsets 16*lane .. 16*lane+15
    const uv4 bv = *reinterpret_cast<const uv4*>(bm + (size_t)xcol * 8192 + y0 + 16 * lane);
    lds[wv][4 * lane + 0] = bv.x;
    lds[wv][4 * lane + 1] = bv.y;
    lds[wv][4 * lane + 2] = bv.z;
    lds[wv][4 * lane + 3] = bv.w;
    __builtin_amdgcn_s_waitcnt(0);                  // own-wave LDS writes complete

    unsigned w[4];
#pragma unroll
    for (int c = 0; c < 4; ++c)
        w[c] = lds[wv][c * 64 + lane];              // bytes for y = y0 + c*256 + 4*lane + {0..3}

#pragma unroll
    for (int r = 0; r < 8; ++r) {                   // output row x0+r (bit r of each byte)
        int* rowp = out + ((size_t)(x0 + r) << 13) + y0 + 4 * lane;
#pragma unroll
        for (int c = 0; c < 4; ++c) {               // 4 consecutive 1 KB solid chunks
            iv4 o;
            o.x = (int)((w[c] >> (r))      & 1u);
            o.y = (int)((w[c] >> (r + 8))  & 1u);
            o.z = (int)((w[c] >> (r + 16)) & 1u);
            o.w = (int)((w[c] >> (r + 24)) & 1u);
            __builtin_nontemporal_store(o, reinterpret_cast<iv4*>(rowp + c * 256));
        }
    }
}

// ---------------- fallback (round-6, known-good) ----------------
#define BIG4 make_float4(FLT_MAX, FLT_MAX, FLT_MAX, FLT_MAX)

template<bool EDGE>
__device__ __forceinline__ void recon_body(const float* __restrict__ d, float thr,
                                           int* __restrict__ out, int bx, int by, int tid) {
    const int xq = tid & 15;
    const int yq = tid >> 4;
    const int gx = bx * 64 + 4 * xq;
    const int gy = by * 64 + 4 * yq;
    float s[6][6];
#pragma unroll
    for (int j = 0; j < 6; ++j) {
        const int yy = gy - 1 + j;
        float4 a, b, c;
        if (!EDGE) {
            const float4* p = (const float4*)(d + ((size_t)yy << 13) + gx);
            a = p[-1]; b = p[0]; c = p[1];
        } else {
            const bool yok = (unsigned)yy < 8192u;
            const float4* p = (const float4*)(d + ((size_t)(yok ? yy : 0) << 13) + gx);
            a = (yok && gx >= 4)       ? p[-1] : BIG4;
            b = yok                    ? p[0]  : BIG4;
            c = (yok && gx + 7 < 8192) ? p[1]  : BIG4;
        }
        s[j][0] = a.w; s[j][1] = b.x; s[j][2] = b.y;
        s[j][3] = b.z; s[j][4] = b.w; s[j][5] = c.x;
    }
#pragma unroll
    for (int i = 0; i < 4; ++i) {
        int r[4];
#pragma unroll
        for (int k = 0; k < 4; ++k) {
            const float ctr = s[k + 1][i + 1];
            const bool conn = (fabsf(s[k][i]     - ctr) <= thr) |
                              (fabsf(s[k][i + 2] - ctr) <= thr) |
                              (fabsf(s[k + 2][i]     - ctr) <= thr) |
                              (fabsf(s[k + 2][i + 2] - ctr) <= thr);
            r[k] = conn ? 1 : 0;
        }
        *reinterpret_cast<int4*>(out + ((size_t)(gx + i) << 13) + gy) =
            make_int4(r[0], r[1], r[2], r[3]);
    }
}

__global__ __launch_bounds__(256, 4)
void recon_fallback(const float* __restrict__ d, const float* __restrict__ thrp,
                    int* __restrict__ out) {
    const float thr = thrp[0];
    const int bx = blockIdx.x, by = blockIdx.y;
    if (bx >= 1 && bx <= 126 && by >= 1 && by <= 126)
        recon_body<false>(d, thr, out, bx, by, threadIdx.x);
    else
        recon_body<true>(d, thr, out, bx, by, threadIdx.x);
}

extern "C" void kernel_launch(void* const* d_in, const int* in_sizes, int n_in,
                              void* d_out, int out_size, void* d_ws, size_t ws_size,
                              hipStream_t stream) {
    const float* d   = (const float*)d_in[0];
    const float* thr = (const float*)d_in[1];
    int* out = (int*)d_out;
    const size_t BM_BYTES = (size_t)8192 * 1024;   // 8 MB bit-packed mask

    if (ws_size >= BM_BYTES) {
        unsigned char* bm = (unsigned char*)d_ws;
        pass1_kernel<<<1024, 256, 0, stream>>>(d, thr, bm);
        pass2_kernel<<<2048, 256, 0, stream>>>(bm, out);
    } else {
        recon_fallback<<<dim3(128, 128), 256, 0, stream>>>(d, thr, out);
    }
}